// Round 5
// baseline (92.231 us; speedup 1.0000x reference)
//
#include <hip/hip_runtime.h>
#include <math.h>

#define NODES 4096
#define FEATS 256
#define BATCH 1024
#define LR_C 0.5f
#define SIGMA_C 70.4f

typedef _Float16 f16x8 __attribute__((ext_vector_type(8)));
typedef float floatx4 __attribute__((ext_vector_type(4)));

__device__ __forceinline__ void get_params(int it, float& lr, float& r2, float& i2r2) {
    float decay = __expf(-(float)it * (SIGMA_C / 100000.0f));
    float radius = SIGMA_C * decay + 1e-6f;
    lr = LR_C * decay;
    r2 = radius * radius;
    i2r2 = 1.0f / (2.0f * r2);
}

// monotone float -> uint key; u64 key = (fkey << 32) | idx (ties -> smaller idx)
__device__ __forceinline__ unsigned fkey(float f) {
    unsigned u = __float_as_uint(f);
    return (u & 0x80000000u) ? ~u : (u | 0x80000000u);
}
__device__ __forceinline__ unsigned long long shfl_xor_u64(unsigned long long v, int mask) {
    unsigned lo = (unsigned)v, hi = (unsigned)(v >> 32);
    lo = __shfl_xor(lo, mask, 64);
    hi = __shfl_xor(hi, mask, 64);
    return ((unsigned long long)hi << 32) | lo;
}

// ---- K1: gemm1+min, 128n x 64b tile, BK=64 (48 MFMA per wave per barrier-pair).
//      INLINE fp32->fp16-split conversion; sqd via xh*wh + xh*wl + xl*wh MFMA;
//      w2 computed in-block from staged fp32; XT (X^T fp16-hi) emitted by blocks
//      x==k0>>6; per-row packed-u64 atomicMin -> gmin (memset-initialized).
__global__ __launch_bounds__(256) void k_gemm1min(const float* __restrict__ X, const float* __restrict__ Wm,
                                                  _Float16* __restrict__ XT,
                                                  unsigned long long* __restrict__ gmin) {
    __shared__ _Float16 Ah[64][72];
    __shared__ _Float16 Al[64][72];
    __shared__ _Float16 Bh[128][72];
    __shared__ _Float16 Bl[128][72];
    __shared__ unsigned long long rowmin[64][2];
    __shared__ float w2s[128][2];
    const int n0 = blockIdx.x * 128;
    const int b0 = blockIdx.y * 64;
    const int t = threadIdx.x;
    const int wave = t >> 6, lane = t & 63;
    const int wb = wave & 1, wn2 = wave >> 1;   // wave grid: 2(b) x 2(n)
    const int lm = lane & 15, quad = lane >> 4;
    const int xrow = t >> 2, xk = (t & 3) * 16; // X staging: 16 elems/thread
    const int wrow = t >> 1, wk = (t & 1) * 32; // W staging: 32 elems/thread
    float wsq = 0.0f;
    floatx4 acc[2][4] = {};                     // [bf][nf]
    for (int k0 = 0; k0 < FEATS; k0 += 64) {
        // stage X (64 rows x 64 k) -> Ah/Al, chunks of 8
#pragma unroll
        for (int ch = 0; ch < 2; ++ch) {
            float a[8];
            *(float4*)&a[0] = *(const float4*)&X[(size_t)(b0 + xrow) * FEATS + k0 + xk + ch * 8];
            *(float4*)&a[4] = *(const float4*)&X[(size_t)(b0 + xrow) * FEATS + k0 + xk + ch * 8 + 4];
            union { _Float16 h[8]; float4 q; } hh, ll;
#pragma unroll
            for (int i = 0; i < 8; ++i) {
                hh.h[i] = (_Float16)a[i];
                ll.h[i] = (_Float16)(a[i] - (float)hh.h[i]);
            }
            *(float4*)&Ah[xrow][xk + ch * 8] = hh.q;
            *(float4*)&Al[xrow][xk + ch * 8] = ll.q;
        }
        // stage W (128 rows x 64 k) -> Bh/Bl, chunks of 8; accumulate w2 partial
#pragma unroll
        for (int ch = 0; ch < 4; ++ch) {
            float a[8];
            *(float4*)&a[0] = *(const float4*)&Wm[(size_t)(n0 + wrow) * FEATS + k0 + wk + ch * 8];
            *(float4*)&a[4] = *(const float4*)&Wm[(size_t)(n0 + wrow) * FEATS + k0 + wk + ch * 8 + 4];
            union { _Float16 h[8]; float4 q; } hh, ll;
#pragma unroll
            for (int i = 0; i < 8; ++i) {
                hh.h[i] = (_Float16)a[i];
                ll.h[i] = (_Float16)(a[i] - (float)hh.h[i]);
                wsq += a[i] * a[i];
            }
            *(float4*)&Bh[wrow][wk + ch * 8] = hh.q;
            *(float4*)&Bl[wrow][wk + ch * 8] = ll.q;
        }
        __syncthreads();
#pragma unroll
        for (int ks = 0; ks < 64; ks += 32) {
            f16x8 xh[2], xl[2], wh[4], wl[4];
#pragma unroll
            for (int bf = 0; bf < 2; ++bf) {
                xh[bf] = *(f16x8*)&Ah[wb * 32 + bf * 16 + lm][ks + quad * 8];
                xl[bf] = *(f16x8*)&Al[wb * 32 + bf * 16 + lm][ks + quad * 8];
            }
#pragma unroll
            for (int nf = 0; nf < 4; ++nf) {
                wh[nf] = *(f16x8*)&Bh[wn2 * 64 + nf * 16 + lm][ks + quad * 8];
                wl[nf] = *(f16x8*)&Bl[wn2 * 64 + nf * 16 + lm][ks + quad * 8];
            }
#pragma unroll
            for (int bf = 0; bf < 2; ++bf)
#pragma unroll
                for (int nf = 0; nf < 4; ++nf) {
                    acc[bf][nf] = __builtin_amdgcn_mfma_f32_16x16x32_f16(xh[bf], wh[nf], acc[bf][nf], 0, 0, 0);
                    acc[bf][nf] = __builtin_amdgcn_mfma_f32_16x16x32_f16(xh[bf], wl[nf], acc[bf][nf], 0, 0, 0);
                    acc[bf][nf] = __builtin_amdgcn_mfma_f32_16x16x32_f16(xl[bf], wh[nf], acc[bf][nf], 0, 0, 0);
                }
        }
        // XT emission: block x == k0>>6 writes X^T-hi d-rows k0..k0+63 for its b-range
        if (blockIdx.x == (k0 >> 6)) {
            const int dcol = t >> 2, bch = (t & 3) * 16;
            union { _Float16 h[16]; float4 q[2]; } u;
#pragma unroll
            for (int j = 0; j < 16; ++j) u.h[j] = Ah[bch + j][dcol];
            *(float4*)&XT[(size_t)(k0 + dcol) * BATCH + b0 + bch] = u.q[0];
            *(float4*)&XT[(size_t)(k0 + dcol) * BATCH + b0 + bch + 8] = u.q[1];
        }
        __syncthreads();
    }
    w2s[wrow][t & 1] = wsq;
    __syncthreads();
    // epilogue: per-lane 4 n-cols; rows = wb*32 + bf*16 + quad*4 + r
    int colg[4];
    float w2c[4];
#pragma unroll
    for (int nf = 0; nf < 4; ++nf) {
        int rt = wn2 * 64 + nf * 16 + lm;
        colg[nf] = n0 + rt;
        w2c[nf] = w2s[rt][0] + w2s[rt][1];
    }
#pragma unroll
    for (int bf = 0; bf < 2; ++bf) {
#pragma unroll
        for (int r = 0; r < 4; ++r) {
            unsigned long long m = 0xFFFFFFFFFFFFFFFFULL;
#pragma unroll
            for (int nf = 0; nf < 4; ++nf) {
                float v = w2c[nf] - 2.0f * acc[bf][nf][r];
                unsigned long long k = ((unsigned long long)fkey(v) << 32) | (unsigned)colg[nf];
                if (k < m) m = k;
            }
#pragma unroll
            for (int mk = 1; mk < 16; mk <<= 1) {
                unsigned long long o = shfl_xor_u64(m, mk);
                if (o < m) m = o;
            }
            if (lm == 0) rowmin[wb * 32 + bf * 16 + quad * 4 + r][wn2] = m;
        }
    }
    __syncthreads();
    if (t < 64) {
        unsigned long long v = rowmin[t][0];
        if (rowmin[t][1] < v) v = rowmin[t][1];
        atomicMin(&gmin[b0 + t], v);
    }
}

// ---- K2 (fused): gemm2 with on-the-fly A-tile generation from gmin.
//      A[n][b] = lr_op^T computed in-kernel, per-block row-sum replaces Svec,
//      out1 written by d0==0 blocks. Epilogue: out0 = Wm*(1 - rowsum/B) + acc/B.
__global__ __launch_bounds__(256) void k_gemm2f(const _Float16* __restrict__ XT,
                                                const unsigned long long* __restrict__ gmin,
                                                const int* __restrict__ itp,
                                                const float* __restrict__ Wm,
                                                float* __restrict__ out0, float* __restrict__ out1) {
    __shared__ _Float16 As[32][136];
    __shared__ _Float16 Bs[64][136];
    __shared__ int bmu_s[1024];
    __shared__ float Svl[32];
    const int d0 = blockIdx.x * 64;
    const int n0 = blockIdx.y * 32;
    const int t = threadIdx.x;
    const int wave = t >> 6, lane = t & 63;
    const int wm = wave & 1, wn = wave >> 1;
    const int lm = lane & 15, quad = lane >> 4;

#pragma unroll
    for (int j = 0; j < 4; ++j)
        bmu_s[t + j * 256] = (int)(gmin[t + j * 256] & 0xFFFFFFFFULL);
    float lr, r2, i2r2;
    get_params(itp[0], lr, r2, i2r2);
    if (blockIdx.x == 0 && blockIdx.y < 4)
        out1[blockIdx.y * 256 + t] = (float)(int)(gmin[blockIdx.y * 256 + t] & 0xFFFFFFFFULL);
    __syncthreads();

    // A-gen geometry: 32 rows x 128 cols per K-step, 16 cols/thread
    const int arow = t >> 3, ac = (t & 7) * 16;
    const int nn = n0 + arow;
    const int ni = nn >> 6, nj = nn & 63;
    // B staging geometry
    const int brow = t >> 2, bcoff = (t & 3) * 32;

    float ssum = 0.0f;
    floatx4 acc0 = {}, acc1 = {};
    for (int k0 = 0; k0 < BATCH; k0 += 128) {
        union { _Float16 h[16]; float4 q[2]; } u;
#pragma unroll
        for (int c = 0; c < 16; ++c) {
            int m = bmu_s[k0 + ac + c];
            int di = ni - (m >> 6); di = di < 0 ? -di : di;
            int dj = nj - (m & 63); dj = dj < 0 ? -dj : dj;
            float d2f = (float)(di * di + dj * dj);
            float val = (d2f <= r2) ? lr * __expf(-d2f * i2r2) : 0.0f;
            u.h[c] = (_Float16)val;
            ssum += val;
        }
        *(float4*)&As[arow][ac] = u.q[0];
        *(float4*)&As[arow][ac + 8] = u.q[1];
#pragma unroll
        for (int c = 0; c < 4; ++c)
            *(float4*)&Bs[brow][bcoff + c * 8] =
                *(const float4*)&XT[(size_t)(d0 + brow) * BATCH + k0 + bcoff + c * 8];
        __syncthreads();
#pragma unroll
        for (int ks = 0; ks < 128; ks += 32) {
            f16x8 a = *(f16x8*)&As[wm * 16 + lm][ks + quad * 8];
            f16x8 b0 = *(f16x8*)&Bs[wn * 32 + lm][ks + quad * 8];
            f16x8 b1 = *(f16x8*)&Bs[wn * 32 + 16 + lm][ks + quad * 8];
            acc0 = __builtin_amdgcn_mfma_f32_16x16x32_f16(a, b0, acc0, 0, 0, 0);
            acc1 = __builtin_amdgcn_mfma_f32_16x16x32_f16(a, b1, acc1, 0, 0, 0);
        }
        __syncthreads();
    }
#pragma unroll
    for (int mk = 1; mk < 8; mk <<= 1) ssum += __shfl_xor(ssum, mk, 64);
    if ((t & 7) == 0) Svl[arow] = ssum;
    __syncthreads();

    const float invB = 1.0f / (float)BATCH;
#pragma unroll
    for (int r = 0; r < 4; ++r) {
        int rowN = n0 + wm * 16 + quad * 4 + r;
        float cc = 1.0f - Svl[rowN - n0] * invB;
        int col0 = d0 + wn * 32 + lm;
        int col1 = col0 + 16;
        out0[(size_t)rowN * FEATS + col0] = Wm[(size_t)rowN * FEATS + col0] * cc + acc0[r] * invB;
        out0[(size_t)rowN * FEATS + col1] = Wm[(size_t)rowN * FEATS + col1] * cc + acc1[r] * invB;
    }
}

extern "C" void kernel_launch(void* const* d_in, const int* in_sizes, int n_in,
                              void* d_out, int out_size, void* d_ws, size_t ws_size,
                              hipStream_t stream) {
    const float* X = (const float*)d_in[0];    // (1024, 256)
    const float* Wm = (const float*)d_in[1];   // (4096, 256)
    const int* itp = (const int*)d_in[2];      // scalar iteration
    float* out0 = (float*)d_out;
    float* out1 = out0 + (size_t)NODES * FEATS;

    char* ws = (char*)d_ws;
    _Float16* XT = (_Float16*)(ws + 0);                              // 512 KB
    unsigned long long* gmin = (unsigned long long*)(ws + 524288);   // 8 KB

    hipMemsetAsync(gmin, 0xFF, 1024 * sizeof(unsigned long long), stream);
    k_gemm1min<<<dim3(32, 16), 256, 0, stream>>>(X, Wm, XT, gmin);
    k_gemm2f<<<dim3(4, 128), 256, 0, stream>>>(XT, gmin, itp, Wm, out0, out1);
}

// Round 6
// 89.029 us; speedup vs baseline: 1.0360x; 1.0360x over previous
//
#include <hip/hip_runtime.h>
#include <math.h>

#define NODES 4096
#define FEATS 256
#define BATCH 1024
#define LR_C 0.5f
#define SIGMA_C 70.4f

typedef _Float16 f16x8 __attribute__((ext_vector_type(8)));
typedef float floatx4 __attribute__((ext_vector_type(4)));

__device__ __forceinline__ void get_params(int it, float& lr, float& r2, float& i2r2) {
    float decay = __expf(-(float)it * (SIGMA_C / 100000.0f));
    float radius = SIGMA_C * decay + 1e-6f;
    lr = LR_C * decay;
    r2 = radius * radius;
    i2r2 = 1.0f / (2.0f * r2);
}

// monotone float -> uint key; u64 key = (fkey << 32) | idx (ties -> smaller idx)
__device__ __forceinline__ unsigned fkey(float f) {
    unsigned u = __float_as_uint(f);
    return (u & 0x80000000u) ? ~u : (u | 0x80000000u);
}
__device__ __forceinline__ unsigned long long shfl_xor_u64(unsigned long long v, int mask) {
    unsigned lo = (unsigned)v, hi = (unsigned)(v >> 32);
    lo = __shfl_xor(lo, mask, 64);
    hi = __shfl_xor(hi, mask, 64);
    return ((unsigned long long)hi << 32) | lo;
}

// ---- K1: gemm1+min, 128n x 64b tile, BK=32 (24 MFMA per wave per barrier-pair,
//      LDS ~33 KB -> ~4 blocks/CU). INLINE fp32->fp16-split conversion; sqd via
//      xh*wh + xh*wl + xl*wh MFMA; w2 in-block from staged fp32; XT (X^T fp16-hi)
//      emitted by blocks x==kstep; per-row packed-u64 atomicMin -> gmin (memset-init).
__global__ __launch_bounds__(256) void k_gemm1min(const float* __restrict__ X, const float* __restrict__ Wm,
                                                  _Float16* __restrict__ XT,
                                                  unsigned long long* __restrict__ gmin) {
    __shared__ _Float16 Ah[64][40];
    __shared__ _Float16 Al[64][40];
    __shared__ _Float16 Bh[128][40];
    __shared__ _Float16 Bl[128][40];
    __shared__ unsigned long long rowmin[64][2];
    __shared__ float w2s[128][2];
    const int n0 = blockIdx.x * 128;
    const int b0 = blockIdx.y * 64;
    const int t = threadIdx.x;
    const int wave = t >> 6, lane = t & 63;
    const int wb = wave & 1, wn2 = wave >> 1;   // wave grid: 2(b) x 2(n)
    const int lm = lane & 15, quad = lane >> 4;
    const int xrow = t >> 2, xk = (t & 3) * 8;  // X staging: 8 elems/thread
    const int wrow = t >> 1, wk = (t & 1) * 16; // W staging: 16 elems/thread
    float wsq = 0.0f;
    floatx4 acc[2][4] = {};                     // [bf][nf]
    for (int k0 = 0; k0 < FEATS; k0 += 32) {
        // stage X (64 rows x 32 k) -> Ah/Al
        {
            float a[8];
            *(float4*)&a[0] = *(const float4*)&X[(size_t)(b0 + xrow) * FEATS + k0 + xk];
            *(float4*)&a[4] = *(const float4*)&X[(size_t)(b0 + xrow) * FEATS + k0 + xk + 4];
            union { _Float16 h[8]; float4 q; } hh, ll;
#pragma unroll
            for (int i = 0; i < 8; ++i) {
                hh.h[i] = (_Float16)a[i];
                ll.h[i] = (_Float16)(a[i] - (float)hh.h[i]);
            }
            *(float4*)&Ah[xrow][xk] = hh.q;
            *(float4*)&Al[xrow][xk] = ll.q;
        }
        // stage W (128 rows x 32 k) -> Bh/Bl; accumulate w2 partial
#pragma unroll
        for (int ch = 0; ch < 2; ++ch) {
            float a[8];
            *(float4*)&a[0] = *(const float4*)&Wm[(size_t)(n0 + wrow) * FEATS + k0 + wk + ch * 8];
            *(float4*)&a[4] = *(const float4*)&Wm[(size_t)(n0 + wrow) * FEATS + k0 + wk + ch * 8 + 4];
            union { _Float16 h[8]; float4 q; } hh, ll;
#pragma unroll
            for (int i = 0; i < 8; ++i) {
                hh.h[i] = (_Float16)a[i];
                ll.h[i] = (_Float16)(a[i] - (float)hh.h[i]);
                wsq += a[i] * a[i];
            }
            *(float4*)&Bh[wrow][wk + ch * 8] = hh.q;
            *(float4*)&Bl[wrow][wk + ch * 8] = ll.q;
        }
        __syncthreads();
        {
            f16x8 xh[2], xl[2], wh[4], wl[4];
#pragma unroll
            for (int bf = 0; bf < 2; ++bf) {
                xh[bf] = *(f16x8*)&Ah[wb * 32 + bf * 16 + lm][quad * 8];
                xl[bf] = *(f16x8*)&Al[wb * 32 + bf * 16 + lm][quad * 8];
            }
#pragma unroll
            for (int nf = 0; nf < 4; ++nf) {
                wh[nf] = *(f16x8*)&Bh[wn2 * 64 + nf * 16 + lm][quad * 8];
                wl[nf] = *(f16x8*)&Bl[wn2 * 64 + nf * 16 + lm][quad * 8];
            }
#pragma unroll
            for (int bf = 0; bf < 2; ++bf)
#pragma unroll
                for (int nf = 0; nf < 4; ++nf) {
                    acc[bf][nf] = __builtin_amdgcn_mfma_f32_16x16x32_f16(xh[bf], wh[nf], acc[bf][nf], 0, 0, 0);
                    acc[bf][nf] = __builtin_amdgcn_mfma_f32_16x16x32_f16(xh[bf], wl[nf], acc[bf][nf], 0, 0, 0);
                    acc[bf][nf] = __builtin_amdgcn_mfma_f32_16x16x32_f16(xl[bf], wh[nf], acc[bf][nf], 0, 0, 0);
                }
        }
        // XT emission: block x == kstep writes X^T-hi d-rows k0..k0+31 for its b-range
        if (blockIdx.x == (k0 >> 5)) {
            const int dcol = t >> 3, bch = (t & 7) * 8;
            union { _Float16 h[8]; float4 q; } u;
#pragma unroll
            for (int j = 0; j < 8; ++j) u.h[j] = Ah[bch + j][dcol];
            *(float4*)&XT[(size_t)(k0 + dcol) * BATCH + b0 + bch] = u.q;
        }
        __syncthreads();
    }
    w2s[wrow][t & 1] = wsq;
    __syncthreads();
    // epilogue: per-lane 4 n-cols; rows = wb*32 + bf*16 + quad*4 + r
    int colg[4];
    float w2c[4];
#pragma unroll
    for (int nf = 0; nf < 4; ++nf) {
        int rt = wn2 * 64 + nf * 16 + lm;
        colg[nf] = n0 + rt;
        w2c[nf] = w2s[rt][0] + w2s[rt][1];
    }
#pragma unroll
    for (int bf = 0; bf < 2; ++bf) {
#pragma unroll
        for (int r = 0; r < 4; ++r) {
            unsigned long long m = 0xFFFFFFFFFFFFFFFFULL;
#pragma unroll
            for (int nf = 0; nf < 4; ++nf) {
                float v = w2c[nf] - 2.0f * acc[bf][nf][r];
                unsigned long long k = ((unsigned long long)fkey(v) << 32) | (unsigned)colg[nf];
                if (k < m) m = k;
            }
#pragma unroll
            for (int mk = 1; mk < 16; mk <<= 1) {
                unsigned long long o = shfl_xor_u64(m, mk);
                if (o < m) m = o;
            }
            if (lm == 0) rowmin[wb * 32 + bf * 16 + quad * 4 + r][wn2] = m;
        }
    }
    __syncthreads();
    if (t < 64) {
        unsigned long long v = rowmin[t][0];
        if (rowmin[t][1] < v) v = rowmin[t][1];
        atomicMin(&gmin[b0 + t], v);
    }
}

// ---- K2 (fused): gemm2 with on-the-fly A-tile generation from gmin.
//      A[n][b] = lr_op^T computed in-kernel, per-block row-sum replaces Svec,
//      out1 written by d0==0 blocks. Epilogue: out0 = Wm*(1 - rowsum/B) + acc/B.
__global__ __launch_bounds__(256) void k_gemm2f(const _Float16* __restrict__ XT,
                                                const unsigned long long* __restrict__ gmin,
                                                const int* __restrict__ itp,
                                                const float* __restrict__ Wm,
                                                float* __restrict__ out0, float* __restrict__ out1) {
    __shared__ _Float16 As[32][136];
    __shared__ _Float16 Bs[64][136];
    __shared__ int bmu_s[1024];
    __shared__ float Svl[32];
    const int d0 = blockIdx.x * 64;
    const int n0 = blockIdx.y * 32;
    const int t = threadIdx.x;
    const int wave = t >> 6, lane = t & 63;
    const int wm = wave & 1, wn = wave >> 1;
    const int lm = lane & 15, quad = lane >> 4;

#pragma unroll
    for (int j = 0; j < 4; ++j)
        bmu_s[t + j * 256] = (int)(gmin[t + j * 256] & 0xFFFFFFFFULL);
    float lr, r2, i2r2;
    get_params(itp[0], lr, r2, i2r2);
    if (blockIdx.x == 0 && blockIdx.y < 4)
        out1[blockIdx.y * 256 + t] = (float)(int)(gmin[blockIdx.y * 256 + t] & 0xFFFFFFFFULL);
    __syncthreads();

    // A-gen geometry: 32 rows x 128 cols per K-step, 16 cols/thread
    const int arow = t >> 3, ac = (t & 7) * 16;
    const int nn = n0 + arow;
    const int ni = nn >> 6, nj = nn & 63;
    // B staging geometry
    const int brow = t >> 2, bcoff = (t & 3) * 32;

    float ssum = 0.0f;
    floatx4 acc0 = {}, acc1 = {};
    for (int k0 = 0; k0 < BATCH; k0 += 128) {
        union { _Float16 h[16]; float4 q[2]; } u;
#pragma unroll
        for (int c = 0; c < 16; ++c) {
            int m = bmu_s[k0 + ac + c];
            int di = ni - (m >> 6); di = di < 0 ? -di : di;
            int dj = nj - (m & 63); dj = dj < 0 ? -dj : dj;
            float d2f = (float)(di * di + dj * dj);
            float val = (d2f <= r2) ? lr * __expf(-d2f * i2r2) : 0.0f;
            u.h[c] = (_Float16)val;
            ssum += val;
        }
        *(float4*)&As[arow][ac] = u.q[0];
        *(float4*)&As[arow][ac + 8] = u.q[1];
#pragma unroll
        for (int c = 0; c < 4; ++c)
            *(float4*)&Bs[brow][bcoff + c * 8] =
                *(const float4*)&XT[(size_t)(d0 + brow) * BATCH + k0 + bcoff + c * 8];
        __syncthreads();
#pragma unroll
        for (int ks = 0; ks < 128; ks += 32) {
            f16x8 a = *(f16x8*)&As[wm * 16 + lm][ks + quad * 8];
            f16x8 b0 = *(f16x8*)&Bs[wn * 32 + lm][ks + quad * 8];
            f16x8 b1 = *(f16x8*)&Bs[wn * 32 + 16 + lm][ks + quad * 8];
            acc0 = __builtin_amdgcn_mfma_f32_16x16x32_f16(a, b0, acc0, 0, 0, 0);
            acc1 = __builtin_amdgcn_mfma_f32_16x16x32_f16(a, b1, acc1, 0, 0, 0);
        }
        __syncthreads();
    }
#pragma unroll
    for (int mk = 1; mk < 8; mk <<= 1) ssum += __shfl_xor(ssum, mk, 64);
    if ((t & 7) == 0) Svl[arow] = ssum;
    __syncthreads();

    const float invB = 1.0f / (float)BATCH;
#pragma unroll
    for (int r = 0; r < 4; ++r) {
        int rowN = n0 + wm * 16 + quad * 4 + r;
        float cc = 1.0f - Svl[rowN - n0] * invB;
        int col0 = d0 + wn * 32 + lm;
        int col1 = col0 + 16;
        out0[(size_t)rowN * FEATS + col0] = Wm[(size_t)rowN * FEATS + col0] * cc + acc0[r] * invB;
        out0[(size_t)rowN * FEATS + col1] = Wm[(size_t)rowN * FEATS + col1] * cc + acc1[r] * invB;
    }
}

extern "C" void kernel_launch(void* const* d_in, const int* in_sizes, int n_in,
                              void* d_out, int out_size, void* d_ws, size_t ws_size,
                              hipStream_t stream) {
    const float* X = (const float*)d_in[0];    // (1024, 256)
    const float* Wm = (const float*)d_in[1];   // (4096, 256)
    const int* itp = (const int*)d_in[2];      // scalar iteration
    float* out0 = (float*)d_out;
    float* out1 = out0 + (size_t)NODES * FEATS;

    char* ws = (char*)d_ws;
    _Float16* XT = (_Float16*)(ws + 0);                              // 512 KB
    unsigned long long* gmin = (unsigned long long*)(ws + 524288);   // 8 KB

    hipMemsetAsync(gmin, 0xFF, 1024 * sizeof(unsigned long long), stream);
    k_gemm1min<<<dim3(32, 16), 256, 0, stream>>>(X, Wm, XT, gmin);
    k_gemm2f<<<dim3(4, 128), 256, 0, stream>>>(XT, gmin, itp, Wm, out0, out1);
}